// Round 2
// baseline (711.113 us; speedup 1.0000x reference)
//
#include <hip/hip_runtime.h>
#include <hip/hip_bf16.h>
#include <stdint.h>

// LightGCN on MI355X, round 2.
// y = D^{-1/2} A^T D^{-1/2} x  ==>  pre-scale z = dinv*x once per layer (fused
// into the epilogue), aggregation becomes an unweighted gather-sum: no per-edge
// norm array needed (halves the k_fill scatter amplification), and z is stored
// bf16 (halves the random row-gather traffic; accumulation stays fp32).

#define N_NODES 100000
#define N_EDGES 3200000
#define DIM 64

#define SCAN_BLOCK 256
#define SCAN_ITEMS 8
#define SCAN_CHUNK (SCAN_BLOCK * SCAN_ITEMS)  // 2048
#define SCAN_NBLOCKS ((N_NODES + SCAN_CHUNK - 1) / SCAN_CHUNK)  // 49

__global__ void k_count_deg(const int* __restrict__ col, int* __restrict__ deg) {
    int e = blockIdx.x * blockDim.x + threadIdx.x;
    if (e < N_EDGES) atomicAdd(&deg[col[e]], 1);
}

__global__ void k_dinv(const int* __restrict__ deg, float* __restrict__ dinv) {
    int i = blockIdx.x * blockDim.x + threadIdx.x;
    if (i < N_NODES) {
        int d = deg[i];
        dinv[i] = (d > 0) ? rsqrtf((float)d) : 0.0f;
    }
}

// Per-block exclusive scan of deg -> base; block totals -> bsums.
__global__ void k_scan1(const int* __restrict__ deg, int* __restrict__ base,
                        int* __restrict__ bsums) {
    int t = threadIdx.x;
    int blockStart = blockIdx.x * SCAN_CHUNK;
    int idx0 = blockStart + t * SCAN_ITEMS;

    int v[SCAN_ITEMS];
    int s = 0;
#pragma unroll
    for (int k = 0; k < SCAN_ITEMS; k++) {
        int idx = idx0 + k;
        v[k] = (idx < N_NODES) ? deg[idx] : 0;
        s += v[k];
    }

    int lane = t & 63;
    int waveId = t >> 6;
    int sum = s;
#pragma unroll
    for (int off = 1; off < 64; off <<= 1) {
        int u = __shfl_up(sum, off);
        if (lane >= off) sum += u;
    }
    int exclusive = sum - s;

    __shared__ int waveTotals[4];
    if (lane == 63) waveTotals[waveId] = sum;
    __syncthreads();
    int waveOff = 0;
    for (int w = 0; w < waveId; w++) waveOff += waveTotals[w];

    int run = exclusive + waveOff;
#pragma unroll
    for (int k = 0; k < SCAN_ITEMS; k++) {
        int idx = idx0 + k;
        if (idx < N_NODES) base[idx] = run;
        run += v[k];
    }
    if (t == SCAN_BLOCK - 1) bsums[blockIdx.x] = run;
}

__global__ void k_scan2(int* __restrict__ bsums, int numBlocks) {
    int lane = threadIdx.x;
    int v = (lane < numBlocks) ? bsums[lane] : 0;
    int sum = v;
#pragma unroll
    for (int off = 1; off < 64; off <<= 1) {
        int u = __shfl_up(sum, off);
        if (lane >= off) sum += u;
    }
    if (lane < numBlocks) bsums[lane] = sum - v;
}

// Finalize base and initialize cursor = base (fill uses cursor directly).
__global__ void k_scan3(int* __restrict__ base, const int* __restrict__ bsums,
                        int* __restrict__ cursor) {
    int i = blockIdx.x * blockDim.x + threadIdx.x;
    if (i < N_NODES) {
        int b = base[i] + bsums[i / SCAN_CHUNK];
        base[i] = b;
        cursor[i] = b;
    }
}

__global__ void k_fill(const int* __restrict__ ei, int* __restrict__ cursor,
                       int* __restrict__ csrc) {
    int e = blockIdx.x * blockDim.x + threadIdx.x;
    if (e >= N_EDGES) return;
    int r = ei[e];
    int c = ei[N_EDGES + e];
    int p = atomicAdd(&cursor[c], 1);
    csrc[p] = r;
}

// z0 = bf16(emb * dinv[node])
__global__ void k_z0(const float* __restrict__ emb, const float* __restrict__ dinv,
                     __hip_bfloat16* __restrict__ z) {
    int o = blockIdx.x * blockDim.x + threadIdx.x;
    if (o < N_NODES * DIM) z[o] = __float2bfloat16(emb[o] * dinv[o >> 6]);
}

// One wave per destination node; lane = feature dim. a = sum z[src]; x' = a*dinv.
// mode 0: acc = emb + x'; znext = bf16(x'*dinv)
// mode 1: acc += x';      znext = bf16(x'*dinv)
// mode 2: acc = (acc + x') * 0.25
__global__ __launch_bounds__(256) void k_spmv(
    const int* __restrict__ base, const int* __restrict__ deg,
    const int* __restrict__ csrc, const __hip_bfloat16* __restrict__ z,
    const float* __restrict__ dinv, __hip_bfloat16* __restrict__ znext,
    const float* __restrict__ emb, float* __restrict__ acc, int mode) {
    int wave = (blockIdx.x * blockDim.x + threadIdx.x) >> 6;
    int lane = threadIdx.x & 63;
    if (wave >= N_NODES) return;

    int start = base[wave];
    int cnt = deg[wave];

    float a = 0.0f;
    int pos = 0;
    while (pos < cnt) {
        int take = min(64, cnt - pos);
        int s = 0;
        if (lane < take) s = csrc[start + pos + lane];
        int j = 0;
        for (; j + 8 <= take; j += 8) {
            int s0 = __shfl(s, j + 0), s1 = __shfl(s, j + 1);
            int s2 = __shfl(s, j + 2), s3 = __shfl(s, j + 3);
            int s4 = __shfl(s, j + 4), s5 = __shfl(s, j + 5);
            int s6 = __shfl(s, j + 6), s7 = __shfl(s, j + 7);
            float v0 = __bfloat162float(z[s0 * DIM + lane]);
            float v1 = __bfloat162float(z[s1 * DIM + lane]);
            float v2 = __bfloat162float(z[s2 * DIM + lane]);
            float v3 = __bfloat162float(z[s3 * DIM + lane]);
            float v4 = __bfloat162float(z[s4 * DIM + lane]);
            float v5 = __bfloat162float(z[s5 * DIM + lane]);
            float v6 = __bfloat162float(z[s6 * DIM + lane]);
            float v7 = __bfloat162float(z[s7 * DIM + lane]);
            a += v0; a += v1; a += v2; a += v3;
            a += v4; a += v5; a += v6; a += v7;
        }
        for (; j < take; j++) {
            int ss = __shfl(s, j);
            a += __bfloat162float(z[ss * DIM + lane]);
        }
        pos += take;
    }

    float di = dinv[wave];
    float xo = a * di;
    int o = wave * DIM + lane;
    if (mode == 0) {
        acc[o] = emb[o] + xo;
        znext[o] = __float2bfloat16(xo * di);
    } else if (mode == 1) {
        acc[o] += xo;
        znext[o] = __float2bfloat16(xo * di);
    } else {
        acc[o] = (acc[o] + xo) * 0.25f;
    }
}

extern "C" void kernel_launch(void* const* d_in, const int* in_sizes, int n_in,
                              void* d_out, int out_size, void* d_ws, size_t ws_size,
                              hipStream_t stream) {
    const float* emb = (const float*)d_in[0];
    const int* ei = (const int*)d_in[1];  // [2, E]: row = ei[0:E], col = ei[E:2E]
    float* out = (float*)d_out;

    char* ws = (char*)d_ws;
    size_t off = 0;
    auto alloc = [&](size_t bytes) -> void* {
        void* p = ws + off;
        off += (bytes + 511) & ~(size_t)511;
        return p;
    };
    int* deg = (int*)alloc((size_t)N_NODES * 4);
    float* dinv = (float*)alloc((size_t)N_NODES * 4);
    int* base = (int*)alloc((size_t)N_NODES * 4);
    int* cursor = (int*)alloc((size_t)N_NODES * 4);
    int* bsums = (int*)alloc(64 * 4);
    int* csrc = (int*)alloc((size_t)N_EDGES * 4);
    __hip_bfloat16* zA = (__hip_bfloat16*)alloc((size_t)N_NODES * DIM * 2);
    __hip_bfloat16* zB = (__hip_bfloat16*)alloc((size_t)N_NODES * DIM * 2);

    hipMemsetAsync(deg, 0, (size_t)N_NODES * 4, stream);

    int eBlocks = (N_EDGES + 255) / 256;
    int nBlocks = (N_NODES + 255) / 256;
    int ndBlocks = (N_NODES * DIM + 255) / 256;

    k_count_deg<<<eBlocks, 256, 0, stream>>>(ei + N_EDGES, deg);
    k_dinv<<<nBlocks, 256, 0, stream>>>(deg, dinv);
    k_scan1<<<SCAN_NBLOCKS, SCAN_BLOCK, 0, stream>>>(deg, base, bsums);
    k_scan2<<<1, 64, 0, stream>>>(bsums, SCAN_NBLOCKS);
    k_scan3<<<nBlocks, 256, 0, stream>>>(base, bsums, cursor);
    k_fill<<<eBlocks, 256, 0, stream>>>(ei, cursor, csrc);
    k_z0<<<ndBlocks, 256, 0, stream>>>(emb, dinv, zA);

    int spmvBlocks = (N_NODES + 3) / 4;  // 4 waves/block, 1 wave/node
    k_spmv<<<spmvBlocks, 256, 0, stream>>>(base, deg, csrc, zA, dinv, zB, emb, out, 0);
    k_spmv<<<spmvBlocks, 256, 0, stream>>>(base, deg, csrc, zB, dinv, zA, emb, out, 1);
    k_spmv<<<spmvBlocks, 256, 0, stream>>>(base, deg, csrc, zA, dinv, zB, emb, out, 2);
}

// Round 3
// 564.342 us; speedup vs baseline: 1.2601x; 1.2601x over previous
//
#include <hip/hip_runtime.h>
#include <hip/hip_bf16.h>
#include <stdint.h>

// LightGCN on MI355X, round 3.
// - CSR build is XCD-bucketed: 8 dst-range buckets, bucket = blockIdx.x & 7
//   (round-robin XCD heuristic). Each bucket's cursor slice (50 KB) + csrc
//   region (~1.6 MB) fit in one XCD's 4 MiB L2 -> local atomics, full-line
//   write combining (kills the 15x scatter write amplification seen in R2).
//   Edges are streamed 8x (L3-served). Correct regardless of XCD mapping.
// - SpMV: wave = dst node; lane layout (g=lane>>3 edge slot, l=lane&7 feature
//   chunk). Each lane gathers 16 B (8 bf16 feats) -> one wave-load = 8 rows
//   (1 KiB). 32-edge unroll = 32 cache lines in flight/wave. shfl_xor reduce.

#define N_NODES 100000
#define N_EDGES 3200000
#define DIM 64

#define NBUCKET 8
#define BUCKET_NODES ((N_NODES + NBUCKET - 1) / NBUCKET)  // 12500
#define SLICE 4096
#define NSLICE ((N_EDGES + SLICE - 1) / SLICE)  // 782

#define SCAN_BLOCK 256
#define SCAN_ITEMS 8
#define SCAN_CHUNK (SCAN_BLOCK * SCAN_ITEMS)  // 2048
#define SCAN_NBLOCKS ((N_NODES + SCAN_CHUNK - 1) / SCAN_CHUNK)  // 49

__device__ __forceinline__ float bl(unsigned u) { return __uint_as_float(u << 16); }
__device__ __forceinline__ float bh(unsigned u) { return __uint_as_float(u & 0xffff0000u); }

// ---- bucketed degree count: deg[c]++ for c in this block's bucket ----
__global__ void k_count_part(const int* __restrict__ ei, int* __restrict__ deg) {
    int b = blockIdx.x & (NBUCKET - 1);
    int m = blockIdx.x >> 3;
    int lo = b * BUCKET_NODES;
    int hi = min(N_NODES, lo + BUCKET_NODES);
    int e0 = m * SLICE;
    int nvec = (min(SLICE, N_EDGES - e0)) >> 2;
    const int4* col4 = (const int4*)(ei + N_EDGES + e0);
    for (int i = threadIdx.x; i < nvec; i += 256) {
        int4 c = col4[i];
        if (c.x >= lo && c.x < hi) atomicAdd(&deg[c.x], 1);
        if (c.y >= lo && c.y < hi) atomicAdd(&deg[c.y], 1);
        if (c.z >= lo && c.z < hi) atomicAdd(&deg[c.z], 1);
        if (c.w >= lo && c.w < hi) atomicAdd(&deg[c.w], 1);
    }
}

__global__ void k_dinv(const int* __restrict__ deg, float* __restrict__ dinv) {
    int i = blockIdx.x * blockDim.x + threadIdx.x;
    if (i < N_NODES) {
        int d = deg[i];
        dinv[i] = (d > 0) ? rsqrtf((float)d) : 0.0f;
    }
}

// ---- exclusive scan of deg -> base ----
__global__ void k_scan1(const int* __restrict__ deg, int* __restrict__ base,
                        int* __restrict__ bsums) {
    int t = threadIdx.x;
    int idx0 = blockIdx.x * SCAN_CHUNK + t * SCAN_ITEMS;

    int v[SCAN_ITEMS];
    int s = 0;
#pragma unroll
    for (int k = 0; k < SCAN_ITEMS; k++) {
        int idx = idx0 + k;
        v[k] = (idx < N_NODES) ? deg[idx] : 0;
        s += v[k];
    }
    int lane = t & 63;
    int waveId = t >> 6;
    int sum = s;
#pragma unroll
    for (int off = 1; off < 64; off <<= 1) {
        int u = __shfl_up(sum, off);
        if (lane >= off) sum += u;
    }
    int exclusive = sum - s;

    __shared__ int waveTotals[4];
    if (lane == 63) waveTotals[waveId] = sum;
    __syncthreads();
    int waveOff = 0;
    for (int w = 0; w < waveId; w++) waveOff += waveTotals[w];

    int run = exclusive + waveOff;
#pragma unroll
    for (int k = 0; k < SCAN_ITEMS; k++) {
        int idx = idx0 + k;
        if (idx < N_NODES) base[idx] = run;
        run += v[k];
    }
    if (t == SCAN_BLOCK - 1) bsums[blockIdx.x] = run;
}

__global__ void k_scan2(int* __restrict__ bsums, int numBlocks) {
    int lane = threadIdx.x;
    int v = (lane < numBlocks) ? bsums[lane] : 0;
    int sum = v;
#pragma unroll
    for (int off = 1; off < 64; off <<= 1) {
        int u = __shfl_up(sum, off);
        if (lane >= off) sum += u;
    }
    if (lane < numBlocks) bsums[lane] = sum - v;
}

__global__ void k_scan3(int* __restrict__ base, const int* __restrict__ bsums,
                        int* __restrict__ cursor) {
    int i = blockIdx.x * blockDim.x + threadIdx.x;
    if (i < N_NODES) {
        int b = base[i] + bsums[i / SCAN_CHUNK];
        base[i] = b;
        cursor[i] = b;
    }
}

// ---- bucketed CSR fill ----
__global__ void k_fill_part(const int* __restrict__ ei, int* __restrict__ cursor,
                            int* __restrict__ csrc) {
    int b = blockIdx.x & (NBUCKET - 1);
    int m = blockIdx.x >> 3;
    int lo = b * BUCKET_NODES;
    int hi = min(N_NODES, lo + BUCKET_NODES);
    int e0 = m * SLICE;
    int nvec = (min(SLICE, N_EDGES - e0)) >> 2;
    const int4* row4 = (const int4*)(ei + e0);
    const int4* col4 = (const int4*)(ei + N_EDGES + e0);
    for (int i = threadIdx.x; i < nvec; i += 256) {
        int4 c = col4[i];
        int4 r = row4[i];
        if (c.x >= lo && c.x < hi) csrc[atomicAdd(&cursor[c.x], 1)] = r.x;
        if (c.y >= lo && c.y < hi) csrc[atomicAdd(&cursor[c.y], 1)] = r.y;
        if (c.z >= lo && c.z < hi) csrc[atomicAdd(&cursor[c.z], 1)] = r.z;
        if (c.w >= lo && c.w < hi) csrc[atomicAdd(&cursor[c.w], 1)] = r.w;
    }
}

// z0 = bf16(emb * dinv[node]) ; vectorized 4 elems/thread
__global__ void k_z0(const float* __restrict__ emb, const float* __restrict__ dinv,
                     __hip_bfloat16* __restrict__ z) {
    int i = blockIdx.x * blockDim.x + threadIdx.x;  // group of 4 elements
    if (i >= (N_NODES * DIM) / 4) return;
    float di = dinv[(i * 4) >> 6];
    const float4 v = ((const float4*)emb)[i];
    union { ushort h[4]; uint2 u; } pk;
    __hip_bfloat16 b0 = __float2bfloat16(v.x * di);
    __hip_bfloat16 b1 = __float2bfloat16(v.y * di);
    __hip_bfloat16 b2 = __float2bfloat16(v.z * di);
    __hip_bfloat16 b3 = __float2bfloat16(v.w * di);
    pk.h[0] = *(ushort*)&b0; pk.h[1] = *(ushort*)&b1;
    pk.h[2] = *(ushort*)&b2; pk.h[3] = *(ushort*)&b3;
    ((uint2*)z)[i] = pk.u;
}

// ---- SpMV: one wave per dst node; 8 rows gathered per wave-load ----
// mode 0: acc = emb + xo; znext = bf16(xo*dinv)
// mode 1: acc += xo;      znext = bf16(xo*dinv)
// mode 2: acc = (acc + xo) * 0.25
__global__ __launch_bounds__(256) void k_spmv(
    const int* __restrict__ base, const int* __restrict__ deg,
    const int* __restrict__ csrc, const __hip_bfloat16* __restrict__ z,
    const float* __restrict__ dinv, __hip_bfloat16* __restrict__ znext,
    const float* __restrict__ emb, float* __restrict__ acc_out, int mode) {
    int wave = (blockIdx.x * blockDim.x + threadIdx.x) >> 6;
    int lane = threadIdx.x & 63;
    if (wave >= N_NODES) return;
    int g = lane >> 3;   // edge slot 0..7
    int l = lane & 7;    // feature chunk: features [l*8, l*8+8)

    int start = base[wave];
    int cnt = deg[wave];

    float acc[8] = {0, 0, 0, 0, 0, 0, 0, 0};

#define ACCUM(U)                                   \
    do {                                           \
        acc[0] += bl((U).x); acc[1] += bh((U).x);  \
        acc[2] += bl((U).y); acc[3] += bh((U).y);  \
        acc[4] += bl((U).z); acc[5] += bh((U).z);  \
        acc[6] += bl((U).w); acc[7] += bh((U).w);  \
    } while (0)

    int pos = 0;
    for (; pos + 32 <= cnt; pos += 32) {
        int i0 = start + pos + g;
        int s0 = csrc[i0];
        int s1 = csrc[i0 + 8];
        int s2 = csrc[i0 + 16];
        int s3 = csrc[i0 + 24];
        uint4 v0 = *((const uint4*)(z + ((size_t)s0 << 6)) + l);
        uint4 v1 = *((const uint4*)(z + ((size_t)s1 << 6)) + l);
        uint4 v2 = *((const uint4*)(z + ((size_t)s2 << 6)) + l);
        uint4 v3 = *((const uint4*)(z + ((size_t)s3 << 6)) + l);
        ACCUM(v0); ACCUM(v1); ACCUM(v2); ACCUM(v3);
    }
    for (; pos < cnt; pos += 8) {
        int idx = pos + g;
        if (idx < cnt) {
            int s = csrc[start + idx];
            uint4 v = *((const uint4*)(z + ((size_t)s << 6)) + l);
            ACCUM(v);
        }
    }
#undef ACCUM

    // reduce across the 8 edge-slot groups (lane bits 3,4,5)
#pragma unroll
    for (int j = 0; j < 8; j++) {
        acc[j] += __shfl_xor(acc[j], 8);
        acc[j] += __shfl_xor(acc[j], 16);
        acc[j] += __shfl_xor(acc[j], 32);
    }

    if (lane < 8) {  // lane == l, holds features [l*8, l*8+8)
        float di = dinv[wave];
        size_t o = (size_t)wave * DIM + lane * 8;
        float xo[8];
#pragma unroll
        for (int j = 0; j < 8; j++) xo[j] = acc[j] * di;

        float4 o0, o1;
        if (mode == 0) {
            float4 e0 = ((const float4*)(emb + o))[0];
            float4 e1 = ((const float4*)(emb + o))[1];
            o0 = make_float4(e0.x + xo[0], e0.y + xo[1], e0.z + xo[2], e0.w + xo[3]);
            o1 = make_float4(e1.x + xo[4], e1.y + xo[5], e1.z + xo[6], e1.w + xo[7]);
        } else if (mode == 1) {
            float4 a0 = ((const float4*)(acc_out + o))[0];
            float4 a1 = ((const float4*)(acc_out + o))[1];
            o0 = make_float4(a0.x + xo[0], a0.y + xo[1], a0.z + xo[2], a0.w + xo[3]);
            o1 = make_float4(a1.x + xo[4], a1.y + xo[5], a1.z + xo[6], a1.w + xo[7]);
        } else {
            float4 a0 = ((const float4*)(acc_out + o))[0];
            float4 a1 = ((const float4*)(acc_out + o))[1];
            o0 = make_float4((a0.x + xo[0]) * 0.25f, (a0.y + xo[1]) * 0.25f,
                             (a0.z + xo[2]) * 0.25f, (a0.w + xo[3]) * 0.25f);
            o1 = make_float4((a1.x + xo[4]) * 0.25f, (a1.y + xo[5]) * 0.25f,
                             (a1.z + xo[6]) * 0.25f, (a1.w + xo[7]) * 0.25f);
        }
        ((float4*)(acc_out + o))[0] = o0;
        ((float4*)(acc_out + o))[1] = o1;

        if (mode != 2) {
            union { ushort h[8]; uint4 u; } pk;
#pragma unroll
            for (int j = 0; j < 8; j++) {
                __hip_bfloat16 b = __float2bfloat16(xo[j] * di);
                pk.h[j] = *(ushort*)&b;
            }
            *((uint4*)(znext + o)) = pk.u;
        }
    }
}

extern "C" void kernel_launch(void* const* d_in, const int* in_sizes, int n_in,
                              void* d_out, int out_size, void* d_ws, size_t ws_size,
                              hipStream_t stream) {
    const float* emb = (const float*)d_in[0];
    const int* ei = (const int*)d_in[1];  // [2, E]: row = ei[0:E], col = ei[E:2E]
    float* out = (float*)d_out;

    char* ws = (char*)d_ws;
    size_t off = 0;
    auto alloc = [&](size_t bytes) -> void* {
        void* p = ws + off;
        off += (bytes + 511) & ~(size_t)511;
        return p;
    };
    int* deg = (int*)alloc((size_t)N_NODES * 4);
    float* dinv = (float*)alloc((size_t)N_NODES * 4);
    int* base = (int*)alloc((size_t)N_NODES * 4);
    int* cursor = (int*)alloc((size_t)N_NODES * 4);
    int* bsums = (int*)alloc(64 * 4);
    int* csrc = (int*)alloc((size_t)N_EDGES * 4);
    __hip_bfloat16* zA = (__hip_bfloat16*)alloc((size_t)N_NODES * DIM * 2);
    __hip_bfloat16* zB = (__hip_bfloat16*)alloc((size_t)N_NODES * DIM * 2);

    hipMemsetAsync(deg, 0, (size_t)N_NODES * 4, stream);

    int nBlocks = (N_NODES + 255) / 256;

    k_count_part<<<NSLICE * NBUCKET, 256, 0, stream>>>(ei, deg);
    k_dinv<<<nBlocks, 256, 0, stream>>>(deg, dinv);
    k_scan1<<<SCAN_NBLOCKS, SCAN_BLOCK, 0, stream>>>(deg, base, bsums);
    k_scan2<<<1, 64, 0, stream>>>(bsums, SCAN_NBLOCKS);
    k_scan3<<<nBlocks, 256, 0, stream>>>(base, bsums, cursor);
    k_fill_part<<<NSLICE * NBUCKET, 256, 0, stream>>>(ei, cursor, csrc);
    k_z0<<<(N_NODES * DIM / 4 + 255) / 256, 256, 0, stream>>>(emb, dinv, zA);

    int spmvBlocks = (N_NODES + 3) / 4;  // 4 waves/block, 1 wave/node
    k_spmv<<<spmvBlocks, 256, 0, stream>>>(base, deg, csrc, zA, dinv, zB, emb, out, 0);
    k_spmv<<<spmvBlocks, 256, 0, stream>>>(base, deg, csrc, zB, dinv, zA, emb, out, 1);
    k_spmv<<<spmvBlocks, 256, 0, stream>>>(base, deg, csrc, zA, dinv, zB, emb, out, 2);
}